// Round 13
// baseline (989.555 us; speedup 1.0000x reference)
//
#include <hip/hip_runtime.h>
#include <cstdint>

using u16 = unsigned short;
using u32 = unsigned int;
typedef __bf16  bf16x8 __attribute__((ext_vector_type(8)));
typedef float   f32x4  __attribute__((ext_vector_type(4)));
typedef float   f32x16 __attribute__((ext_vector_type(16)));

__device__ __forceinline__ u16 f2b(float x) {
    u32 u = __builtin_bit_cast(u32, x);
    u = (u + 0x7fffu + ((u >> 16) & 1u)) >> 16;
    return (u16)u;
}

__device__ __forceinline__ f32x4 mfma16(bf16x8 a, bf16x8 b, f32x4 c) {
    return __builtin_amdgcn_mfma_f32_16x16x32_bf16(a, b, c, 0, 0, 0);
}
__device__ __forceinline__ f32x16 mfma32(bf16x8 a, bf16x8 b, f32x16 c) {
    return __builtin_amdgcn_mfma_f32_32x32x16_bf16(a, b, c, 0, 0, 0);
}

__device__ __forceinline__ void gload16(const void* g, void* lds) {
    auto gp = (__attribute__((address_space(1))) void*)(uintptr_t)g;
    auto lp = (__attribute__((address_space(3))) void*)(uintptr_t)lds;
    __builtin_amdgcn_global_load_lds(gp, lp, 16, 0, 0);
}

// bijective XCD-aware swizzle (m204); bm fastest so co-resident blocks share B panels
__device__ __forceinline__ int2 swz_bmbn(int nbm) {
    const int nwg = gridDim.x, orig = blockIdx.x;
    const int q = nwg >> 3, r = nwg & 7;
    const int xcd = orig & 7, lin = orig >> 3;
    const int id = (xcd < r ? xcd * (q + 1) : r * (q + 1) + (xcd - r) * q) + lin;
    return make_int2(id % nbm, id / nbm);
}

// ---------------------------------------------------------------------------
// Deep-pipelined 128^2 GEMM (ring-4, counted vmcnt, one barrier per half-slot,
// one-slot-ahead regs, R6-style free-scheduled read+MFMA region). 2 blocks/CU.
// EPI: 0 bias->bf16, 1 bias+gelu->bf16, 3 plain f32 (head), 4 f32 split-K
//      partial, 5 bias->bf16 BUT blocks with n0>=2048 (V columns of qkv)
//      write ONLY a transposed copy into out2 [d][t] via LDS.
// ---------------------------------------------------------------------------
template <int KC, int EPI>
__global__ __launch_bounds__(256, 2) void gemm_deep_k(
    const u16* __restrict__ A, int lda, const u16* __restrict__ Bt, int ldb,
    const float* __restrict__ bias, float* __restrict__ outf,
    u16* __restrict__ outb, int N, int nbm, int sk, long long sOut,
    u16* __restrict__ out2)
{
    constexpr int MF   = 4;
    constexpr int NF   = 4;
    constexpr int SLOT = 128 * 32;
    constexpr int HALF = 64 * 32;
    constexpr int H    = KC >> 5;

    __shared__ __align__(16) u16 lds[8 * SLOT];      // 64 KB: lsA | lsB
    u16 (*lsA)[SLOT] = (u16(*)[SLOT])lds;
    u16 (*lsB)[SLOT] = (u16(*)[SLOT])(lds + 4 * SLOT);

    const int s = blockIdx.y;
    A  += (size_t)s * sk;
    Bt += (size_t)s * sk;
    if (EPI == 4) outf += (size_t)s * sOut;

    const int2 bb = swz_bmbn(nbm);
    const int m0 = bb.x * 128, n0 = bb.y * 128;
    const int tid = threadIdx.x;
    const int w = tid >> 6, lane = tid & 63;
    const int wr = (w >> 1) * 64, wc = (w & 1) * 64;
    const int lr = lane & 15, lg = lane >> 4;
    const int rsw = (lg ^ ((lr >> 1) & 3)) * 8;

    const int trow = tid >> 2;
    const int ksw8 = ((tid & 3) ^ ((tid >> 3) & 3)) * 8;
    const u16* aA = A  + (size_t)(m0 + trow) * lda + ksw8;
    const u16* aB = Bt + (size_t)(n0 + trow) * ldb + ksw8;
    u16* dA = lds + trow * 32 + (tid & 3) * 8;
    u16* dB = lds + 4 * SLOT + trow * 32 + (tid & 3) * 8;

    f32x4 acc[MF][NF] = {};

    auto stage = [&](int h) {
        const int sl = h & 3;
        const int koff = h * 32;
        gload16(aA + koff,                     dA + sl * SLOT);
        gload16(aA + koff + (size_t)64 * lda,  dA + sl * SLOT + HALF);
        gload16(aB + koff,                     dB + sl * SLOT);
        gload16(aB + koff + (size_t)64 * ldb,  dB + sl * SLOT + HALF);
    };

    bf16x8 ra0[MF], rb0[NF], ra1[MF], rb1[NF];
    auto lread = [&](bf16x8* af, bf16x8* bf, int h) {
        const int sl = h & 3;
#pragma unroll
        for (int m = 0; m < MF; m++)
            af[m] = *(const bf16x8*)&lsA[sl][(wr + m * 16 + lr) * 32 + rsw];
#pragma unroll
        for (int n = 0; n < NF; n++)
            bf[n] = *(const bf16x8*)&lsB[sl][(wc + n * 16 + lr) * 32 + rsw];
    };

    auto body = [&](int h, bf16x8* aC, bf16x8* bC, bf16x8* aN, bf16x8* bN) {
        if (h + 3 < H) stage(h + 3);
        asm volatile("s_waitcnt lgkmcnt(0)" ::: "memory");
        const int rem = H - 1 - h;
        if (rem >= 3)      asm volatile("s_waitcnt vmcnt(8)" ::: "memory");
        else if (rem == 2) asm volatile("s_waitcnt vmcnt(4)" ::: "memory");
        else if (rem == 1) asm volatile("s_waitcnt vmcnt(0)" ::: "memory");
        __builtin_amdgcn_s_barrier();
        __builtin_amdgcn_sched_barrier(0);
        if (h + 1 < H) lread(aN, bN, h + 1);
        __builtin_amdgcn_s_setprio(1);
#pragma unroll
        for (int m = 0; m < MF; m++)
#pragma unroll
            for (int n = 0; n < NF; n++)
                acc[m][n] = mfma16(aC[m], bC[n], acc[m][n]);
        __builtin_amdgcn_s_setprio(0);
    };

    stage(0); stage(1); stage(2);
    asm volatile("s_waitcnt vmcnt(8)" ::: "memory");
    __builtin_amdgcn_s_barrier();
    lread(ra0, rb0, 0);

#pragma unroll
    for (int h = 0; h < H; h += 2) {
        body(h,     ra0, rb0, ra1, rb1);
        body(h + 1, ra1, rb1, ra0, rb0);
    }

    if constexpr (EPI == 5) {
        if (n0 >= 2048) {
            // V-columns block: write ONLY the transposed tile into out2 [d][t].
            __syncthreads();                          // staging LDS now reusable
            u16* tb = lds;                            // [128 d][132 t] = 33 KB
#pragma unroll
            for (int n = 0; n < NF; n++) {
                const int dl = wc + n * 16 + lr;      // local d
                const float bv = bias[n0 + dl];
#pragma unroll
                for (int m = 0; m < MF; m++) {
                    const int tl = wr + m * 16 + lg * 4;  // local t
#pragma unroll
                    for (int r = 0; r < 4; r++)
                        tb[dl * 132 + tl + r] = f2b(acc[m][n][r] + bv);
                }
            }
            __syncthreads();
#pragma unroll
            for (int it = 0; it < 16; ++it) {
                const int row = it * 8 + (tid >> 5);
                const uint2 v = *(const uint2*)&tb[row * 132 + (tid & 31) * 4];
                *(uint2*)&out2[(size_t)(n0 - 2048 + row) * 2048 + m0 + (tid & 31) * 4] = v;
            }
            return;
        }
    }

#pragma unroll
    for (int n = 0; n < NF; n++) {
        const int gc = n0 + wc + n * 16 + lr;
        float bv = 0.f;
        if constexpr (EPI == 0 || EPI == 1 || EPI == 5) bv = bias[gc];
#pragma unroll
        for (int m = 0; m < MF; m++) {
            const int grb = m0 + wr + m * 16 + lg * 4;
#pragma unroll
            for (int r = 0; r < 4; r++) {
                float v = acc[m][n][r] + bv;
                if constexpr (EPI == 1) v = 0.5f * v * (1.f + erff(v * 0.70710678118654752f));
                const size_t o = (size_t)(grb + r) * N + gc;
                if constexpr (EPI == 3 || EPI == 4) outf[o] = v;
                else                                outb[o] = f2b(v);
            }
        }
    }
}

// ---------------------------------------------------------------------------
// Split-K reduce + residual + bias, fused with the FOLLOWING LayerNorm.
// ---------------------------------------------------------------------------
__global__ __launch_bounds__(256) void reduce_ln_k(
    const float* __restrict__ pbuf, int S,
    const float* __restrict__ bias,
    float* __restrict__ x,
    const float* __restrict__ g, const float* __restrict__ bln,
    u16* __restrict__ hb)
{
    __shared__ float red[8];
    const int row = blockIdx.x, tid = threadIdx.x;
    const int w = tid >> 6, lane = tid & 63;
    const size_t base = (size_t)row * 256 + tid;
    float4 v = ((const float4*)x)[base];
    for (int s = 0; s < S; ++s) {
        const float4 p = ((const float4*)pbuf)[(size_t)s * 524288 + base];
        v.x += p.x; v.y += p.y; v.z += p.z; v.w += p.w;
    }
    const float4 bb = ((const float4*)bias)[tid];
    v.x += bb.x; v.y += bb.y; v.z += bb.z; v.w += bb.w;
    ((float4*)x)[base] = v;

    float s1 = v.x + v.y + v.z + v.w;
#pragma unroll
    for (int d = 1; d < 64; d <<= 1) s1 += __shfl_xor(s1, d);
    if (lane == 0) red[w] = s1;
    __syncthreads();
    const float mu = (red[0] + red[1] + red[2] + red[3]) * (1.f / 1024.f);
    const float d0 = v.x - mu, d1 = v.y - mu, d2 = v.z - mu, d3 = v.w - mu;
    float s2 = d0 * d0 + d1 * d1 + d2 * d2 + d3 * d3;
#pragma unroll
    for (int d = 1; d < 64; d <<= 1) s2 += __shfl_xor(s2, d);
    if (lane == 0) red[4 + w] = s2;
    __syncthreads();
    const float var = (red[4] + red[5] + red[6] + red[7]) * (1.f / 1024.f);
    const float rs = rsqrtf(var + 1e-5f);
    const float4 gv = ((const float4*)g)[tid];
    const float4 bv = ((const float4*)bln)[tid];
    u32 p0 = (u32)f2b(d0 * rs * gv.x + bv.x) | ((u32)f2b(d1 * rs * gv.y + bv.y) << 16);
    u32 p1 = (u32)f2b(d2 * rs * gv.z + bv.z) | ((u32)f2b(d3 * rs * gv.w + bv.w) << 16);
    ((uint2*)(hb + (size_t)row * 1024))[tid] = make_uint2(p0, p1);
}

// ---------------------------------------------------------------------------
// Flash attention, swapped-operand 32x32x16 structure (m214 port).
// ---------------------------------------------------------------------------
__global__ __launch_bounds__(256) void flash_attn_k(
    const u16* __restrict__ qkv, const u16* __restrict__ vT, u16* __restrict__ out)
{
    constexpr int DS = 3072, T = 2048;
    __shared__ float mrg[2][64][32];
    __shared__ float msh[2][32], lsh[2][32];
    __shared__ u16   sbuf[2][32 * 68];
    const int w = threadIdx.x >> 6, lane = threadIdx.x & 63;
    const int lq = lane & 31, hi = lane >> 5;
    const int hoff = blockIdx.y * 64;
    const int pair = w >> 1, par = w & 1;
    const int qt = (pair == 0) ? blockIdx.x : 63 - blockIdx.x;
    const int q0 = qt * 32;
    const int qg = q0 + lq;

    const u16* qp = qkv + (size_t)qg * DS + hoff;
    const u16* kp = qkv + 1024 + hoff;

    bf16x8 qf[4];
#pragma unroll
    for (int d = 0; d < 4; d++)
        qf[d] = *(const bf16x8*)(qp + d * 16 + hi * 8);

    f32x16 o0 = {}, o1 = {};
    float m_r = -1e30f, l_r = 0.f;

    const int ntiles = (qt >> 1) + 1;
    for (int t = par; t < ntiles; t += 2) {
        const int kv0 = t * 64;
        f32x16 s0 = {}, s1 = {};
        {
            const u16* kb0 = kp + (size_t)(kv0 + lq) * DS + hi * 8;
            const u16* kb1 = kb0 + (size_t)32 * DS;
#pragma unroll
            for (int d = 0; d < 4; d++) {
                s0 = mfma32(*(const bf16x8*)(kb0 + d * 16), qf[d], s0);
                s1 = mfma32(*(const bf16x8*)(kb1 + d * 16), qf[d], s1);
            }
        }
        float p[32];
        float mx = -1e30f;
#pragma unroll
        for (int r = 0; r < 16; r++) {
            const int kvl = (r & 3) + 8 * (r >> 2) + 4 * hi;
            float v0 = (kv0 + kvl      <= qg) ? s0[r] * 0.125f : -1e30f;
            float v1 = (kv0 + 32 + kvl <= qg) ? s1[r] * 0.125f : -1e30f;
            p[r] = v0; p[16 + r] = v1;
            mx = fmaxf(mx, fmaxf(v0, v1));
        }
        mx = fmaxf(mx, __shfl_xor(mx, 32));
        const float mn = fmaxf(m_r, mx);
        const float alpha = __expf(m_r - mn);
        m_r = mn;
        float ls = 0.f;
#pragma unroll
        for (int i = 0; i < 32; i++) { p[i] = __expf(p[i] - mn); ls += p[i]; }
        ls += __shfl_xor(ls, 32);
        l_r = l_r * alpha + ls;
#pragma unroll
        for (int r = 0; r < 16; r++) { o0[r] *= alpha; o1[r] *= alpha; }
#pragma unroll
        for (int sub = 0; sub < 2; sub++) {
            u32 pw[8], x[8];
#pragma unroll
            for (int i = 0; i < 8; i++)
                pw[i] = (u32)f2b(p[sub * 16 + 2 * i]) | ((u32)f2b(p[sub * 16 + 2 * i + 1]) << 16);
#pragma unroll
            for (int i = 0; i < 8; i++) x[i] = __shfl_xor(pw[i], 32);
            u32 b0[4], b1[4];
            b0[0] = hi ? x[2]  : pw[0];  b0[1] = hi ? x[3]  : pw[1];
            b0[2] = hi ? pw[2] : x[0];   b0[3] = hi ? pw[3] : x[1];
            b1[0] = hi ? x[6]  : pw[4];  b1[1] = hi ? x[7]  : pw[5];
            b1[2] = hi ? pw[6] : x[4];   b1[3] = hi ? pw[7] : x[5];
            bf16x8 B0 = __builtin_bit_cast(bf16x8, *(const uint4*)b0);
            bf16x8 B1 = __builtin_bit_cast(bf16x8, *(const uint4*)b1);
            const u16* vb = vT + (size_t)(hoff + lq) * T + kv0 + sub * 32 + hi * 8;
            o0 = mfma32(*(const bf16x8*)vb, B0, o0);
            o0 = mfma32(*(const bf16x8*)(vb + 16), B1, o0);
            const u16* vb1 = vb + (size_t)32 * T;
            o1 = mfma32(*(const bf16x8*)vb1, B0, o1);
            o1 = mfma32(*(const bf16x8*)(vb1 + 16), B1, o1);
        }
    }

    __syncthreads();
    if (par == 0) {
#pragma unroll
        for (int r = 0; r < 16; r++) {
            const int d = (r & 3) + 8 * (r >> 2) + 4 * hi;
            mrg[pair][d][lq]      = o0[r];
            mrg[pair][d + 32][lq] = o1[r];
        }
        if (hi == 0) { msh[pair][lq] = m_r; lsh[pair][lq] = l_r; }
    }
    __syncthreads();
    if (par == 1) {
        const float m0v = msh[pair][lq], l0v = lsh[pair][lq];
        const float M = fmaxf(m0v, m_r);
        const float f0 = __expf(m0v - M), f1 = __expf(m_r - M);
        const float linv = 1.f / (l0v * f0 + l_r * f1);
        u32* sb = (u32*)sbuf[pair];
#pragma unroll
        for (int r = 0; r < 16; r += 2) {
            const int d = (r & 3) + 8 * (r >> 2) + 4 * hi;
            float va = (mrg[pair][d][lq] * f0 + o0[r] * f1) * linv;
            float vb = (mrg[pair][d + 1][lq] * f0 + o0[r + 1] * f1) * linv;
            sb[lq * 34 + (d >> 1)] = (u32)f2b(va) | ((u32)f2b(vb) << 16);
            float vc = (mrg[pair][d + 32][lq] * f0 + o1[r] * f1) * linv;
            float vd = (mrg[pair][d + 33][lq] * f0 + o1[r + 1] * f1) * linv;
            sb[lq * 34 + ((d + 32) >> 1)] = (u32)f2b(vc) | ((u32)f2b(vd) << 16);
        }
#pragma unroll
        for (int ps = 0; ps < 8; ps++) {
            const int row = ps * 4 + (lane >> 4);
            const uint2 v = *(const uint2*)&sbuf[pair][row * 68 + (lane & 15) * 4];
            *(uint2*)(out + (size_t)(q0 + row) * 1024 + hoff + (lane & 15) * 4) = v;
        }
    }
}

// ---------------------------------------------------------------------------
// Transpose+convert, 64x64 tile: FULL 128B-line writes. src [K][N] f32 ->
// dst [N][K] bf16, per-z strides.
// ---------------------------------------------------------------------------
__global__ __launch_bounds__(256) void transpose_cvt64_k(
    const float* __restrict__ src, u16* __restrict__ dst, int K, int N,
    long long srcLS, long long dstLS)
{
    __shared__ float tf[64][68];
    src += (size_t)blockIdx.z * srcLS;
    dst += (size_t)blockIdx.z * dstLS;
    const int n0 = blockIdx.x * 64, k0 = blockIdx.y * 64;
    const int tid = threadIdx.x;
    const int c4 = tid & 15, rr = tid >> 4;
#pragma unroll
    for (int p = 0; p < 4; ++p) {
        const int k = rr + p * 16;
        *(float4*)&tf[k][c4 * 4] = *(const float4*)&src[(size_t)(k0 + k) * N + n0 + c4 * 4];
    }
    __syncthreads();
    const int kq = (tid & 15) * 4, nn = tid >> 4;
#pragma unroll
    for (int p = 0; p < 4; ++p) {
        const int n = nn + p * 16;
        const u32 lo = (u32)f2b(tf[kq + 0][n]) | ((u32)f2b(tf[kq + 1][n]) << 16);
        const u32 hi = (u32)f2b(tf[kq + 2][n]) | ((u32)f2b(tf[kq + 3][n]) << 16);
        *(uint2*)&dst[(size_t)(n0 + n) * K + k0 + kq] = make_uint2(lo, hi);
    }
}

// Same, for the 12 q/k/v weight matrices in one launch. z = layer*3 + matrix.
__global__ __launch_bounds__(256) void transpose_cvt64_qkv_k(
    const float* __restrict__ Wq, const float* __restrict__ Wk,
    const float* __restrict__ Wv, u16* __restrict__ qkvT)
{
    __shared__ float tf[64][68];
    const int z = blockIdx.z, l = z / 3, m = z % 3;
    const float* src = (m == 0 ? Wq : (m == 1 ? Wk : Wv)) + (size_t)l * 1048576;
    u16* dst = qkvT + (size_t)l * 3145728 + (size_t)m * 1048576;
    const int n0 = blockIdx.x * 64, k0 = blockIdx.y * 64;
    const int tid = threadIdx.x;
    const int c4 = tid & 15, rr = tid >> 4;
#pragma unroll
    for (int p = 0; p < 4; ++p) {
        const int k = rr + p * 16;
        *(float4*)&tf[k][c4 * 4] = *(const float4*)&src[(size_t)(k0 + k) * 1024 + n0 + c4 * 4];
    }
    __syncthreads();
    const int kq = (tid & 15) * 4, nn = tid >> 4;
#pragma unroll
    for (int p = 0; p < 4; ++p) {
        const int n = nn + p * 16;
        const u32 lo = (u32)f2b(tf[kq + 0][n]) | ((u32)f2b(tf[kq + 1][n]) << 16);
        const u32 hi = (u32)f2b(tf[kq + 2][n]) | ((u32)f2b(tf[kq + 3][n]) << 16);
        *(uint2*)&dst[(size_t)(n0 + n) * 1024 + k0 + kq] = make_uint2(lo, hi);
    }
}

__global__ __launch_bounds__(256) void concat_bias_k(
    const float* __restrict__ bq, const float* __restrict__ bk,
    const float* __restrict__ bv, float* __restrict__ bcat)
{
    const int l = blockIdx.y;
    const int j = blockIdx.x * 256 + threadIdx.x;
    float v;
    if (j < 1024)      v = bq[l * 1024 + j];
    else if (j < 2048) v = bk[l * 1024 + j - 1024];
    else               v = bv[l * 1024 + j - 2048];
    bcat[l * 3072 + j] = v;
}

// ---------------------------------------------------------------------------
// Fused embedding + positional encoding + LayerNorm (ln1 of layer 0).
// ---------------------------------------------------------------------------
__global__ __launch_bounds__(256) void embed_ln_k(
    const int* __restrict__ idx, const float* __restrict__ emb,
    const float* __restrict__ g, const float* __restrict__ b,
    float* __restrict__ x, u16* __restrict__ out)
{
    __shared__ float red[8];
    const int t = blockIdx.x, tid = threadIdx.x;
    const int w = tid >> 6, lane = tid & 63;
    const int tok = idx[t];
    float4 v = ((const float4*)(emb + (size_t)tok * 1024))[tid];
    const int d0i = tid * 4;
    const float c = -0.0089944730195080f;      // -ln(10000)/1024
    const float a0 = (float)t * expf((float)d0i * c);
    const float a1 = (float)t * expf((float)(d0i + 2) * c);
    v.x += sinf(a0); v.y += cosf(a0); v.z += sinf(a1); v.w += cosf(a1);
    ((float4*)(x + (size_t)t * 1024))[tid] = v;

    float s1 = v.x + v.y + v.z + v.w;
#pragma unroll
    for (int d = 1; d < 64; d <<= 1) s1 += __shfl_xor(s1, d);
    if (lane == 0) red[w] = s1;
    __syncthreads();
    const float mu = (red[0] + red[1] + red[2] + red[3]) * (1.f / 1024.f);
    const float d0 = v.x - mu, d1 = v.y - mu, d2 = v.z - mu, d3 = v.w - mu;
    float s2 = d0 * d0 + d1 * d1 + d2 * d2 + d3 * d3;
#pragma unroll
    for (int d = 1; d < 64; d <<= 1) s2 += __shfl_xor(s2, d);
    if (lane == 0) red[4 + w] = s2;
    __syncthreads();
    const float var = (red[4] + red[5] + red[6] + red[7]) * (1.f / 1024.f);
    const float rs = rsqrtf(var + 1e-5f);
    const float4 gv = ((const float4*)g)[tid];
    const float4 bv = ((const float4*)b)[tid];
    u32 p0 = (u32)f2b(d0 * rs * gv.x + bv.x) | ((u32)f2b(d1 * rs * gv.y + bv.y) << 16);
    u32 p1 = (u32)f2b(d2 * rs * gv.z + bv.z) | ((u32)f2b(d3 * rs * gv.w + bv.w) << 16);
    ((uint2*)(out + (size_t)t * 1024))[tid] = make_uint2(p0, p1);
}

// ---------------------------------------------------------------------------
extern "C" void kernel_launch(void* const* d_in, const int* in_sizes, int n_in,
                              void* d_out, int out_size, void* d_ws, size_t ws_size,
                              hipStream_t stream)
{
    const int*   idx   = (const int*)  d_in[0];
    const float* embed = (const float*)d_in[1];
    const float* Wq    = (const float*)d_in[2];
    const float* Wk    = (const float*)d_in[3];
    const float* Wv    = (const float*)d_in[4];
    const float* Wo    = (const float*)d_in[5];
    const float* bq    = (const float*)d_in[6];
    const float* bk    = (const float*)d_in[7];
    const float* bv    = (const float*)d_in[8];
    const float* bo    = (const float*)d_in[9];
    const float* ln1g  = (const float*)d_in[10];
    const float* ln1b  = (const float*)d_in[11];
    const float* ln2g  = (const float*)d_in[12];
    const float* ln2b  = (const float*)d_in[13];
    const float* w1    = (const float*)d_in[14];
    const float* b1    = (const float*)d_in[15];
    const float* w2    = (const float*)d_in[16];
    const float* b2    = (const float*)d_in[17];
    const float* lnfg  = (const float*)d_in[18];
    const float* lnfb  = (const float*)d_in[19];
    const float* headw = (const float*)d_in[20];

    char* ws = (char*)d_ws;
    auto alloc = [&](size_t bytes) {
        char* p = ws;
        ws += (bytes + 255) & ~(size_t)255;
        return p;
    };
    u16*   qkvT = (u16*)alloc((size_t)4 * 3072 * 1024 * 2);
    u16*   WoT  = (u16*)alloc((size_t)4 * 1024 * 1024 * 2);
    u16*   w1T  = (u16*)alloc((size_t)4 * 1024 * 4096 * 2);
    u16*   w2T  = (u16*)alloc((size_t)4 * 1024 * 4096 * 2);
    u16*   hT   = (u16*)alloc((size_t)32000 * 1024 * 2);
    float* bcat = (float*)alloc((size_t)4 * 3072 * 4);
    float* x    = (float*)alloc((size_t)2048 * 1024 * 4);
    u16*   hb   = (u16*)alloc((size_t)2048 * 1024 * 2);
    u16*   qkvb = (u16*)alloc((size_t)2048 * 3072 * 2);
    u16*   vTb  = (u16*)alloc((size_t)2048 * 1024 * 2);
    u16*   ab   = (u16*)alloc((size_t)2048 * 1024 * 2);
    u16*   ff   = (u16*)alloc((size_t)2048 * 4096 * 2);
    float* pbuf = (float*)d_out;   // split-K partials; head GEMM overwrites at the end

    transpose_cvt64_qkv_k<<<dim3(16, 16, 12), 256, 0, stream>>>(Wq, Wk, Wv, qkvT);
    transpose_cvt64_k<<<dim3(16, 16, 4),  256, 0, stream>>>(Wo, WoT,    1024, 1024,  1048576, 1048576);
    transpose_cvt64_k<<<dim3(64, 16, 4),  256, 0, stream>>>(w1, w1T,    1024, 4096,  4194304, 4194304);
    transpose_cvt64_k<<<dim3(16, 64, 4),  256, 0, stream>>>(w2, w2T,    4096, 1024,  4194304, 4194304);
    transpose_cvt64_k<<<dim3(500, 16, 1), 256, 0, stream>>>(headw, hT,  1024, 32000, 0, 0);
    concat_bias_k<<<dim3(12, 4), 256, 0, stream>>>(bq, bk, bv, bcat);

    embed_ln_k<<<dim3(2048), 256, 0, stream>>>(idx, embed, ln1g, ln1b, x, hb);

    for (int l = 0; l < 4; ++l) {
        // qkv: 128^2 deep, N=3072; EPI5 -> V-column blocks write vTb transposed
        gemm_deep_k<1024, 5><<<dim3(384), 256, 0, stream>>>(
            hb, 1024, qkvT + (size_t)l * 3145728, 1024,
            bcat + l * 3072, nullptr, qkvb, 3072, 16, 0, 0, vTb);
        flash_attn_k<<<dim3(32, 16), 256, 0, stream>>>(qkvb, vTb, ab);
        // o-proj: split-K=2 (KC=512)
        gemm_deep_k<512, 4><<<dim3(128, 2), 256, 0, stream>>>(
            ab, 1024, WoT + (size_t)l * 1048576, 1024,
            nullptr, pbuf, nullptr, 1024, 16, 512, 2097152, nullptr);
        reduce_ln_k<<<dim3(2048), 256, 0, stream>>>(pbuf, 2, bo + l * 1024, x,
                                                    ln2g + l * 1024, ln2b + l * 1024, hb);
        // ffn1: gelu, N=4096
        gemm_deep_k<1024, 1><<<dim3(512), 256, 0, stream>>>(
            hb, 1024, w1T + (size_t)l * 4194304, 1024,
            b1 + l * 4096, nullptr, ff, 4096, 16, 0, 0, nullptr);
        // ffn2: split-K=4 (KC=1024 of 4096)
        gemm_deep_k<1024, 4><<<dim3(128, 4), 256, 0, stream>>>(
            ff, 4096, w2T + (size_t)l * 4194304, 4096,
            nullptr, pbuf, nullptr, 1024, 16, 1024, 2097152, nullptr);
        const float* ng = (l < 3) ? (ln1g + (l + 1) * 1024) : lnfg;
        const float* nb = (l < 3) ? (ln1b + (l + 1) * 1024) : lnfb;
        reduce_ln_k<<<dim3(2048), 256, 0, stream>>>(pbuf, 4, b2 + l * 1024, x, ng, nb, hb);
    }
    // head: 128^2 deep at 2 blocks/CU (occupancy lever), grid 16x250 = 4000
    gemm_deep_k<1024, 3><<<dim3(4000), 256, 0, stream>>>(
        hb, 1024, hT, 1024, nullptr, (float*)d_out, nullptr, 32000, 16, 0, 0, nullptr);
}

// Round 14
// 938.945 us; speedup vs baseline: 1.0539x; 1.0539x over previous
//
#include <hip/hip_runtime.h>
#include <cstdint>

using u16 = unsigned short;
using u32 = unsigned int;
typedef __bf16  bf16x8 __attribute__((ext_vector_type(8)));
typedef float   f32x4  __attribute__((ext_vector_type(4)));
typedef float   f32x16 __attribute__((ext_vector_type(16)));

__device__ __forceinline__ u16 f2b(float x) {
    u32 u = __builtin_bit_cast(u32, x);
    u = (u + 0x7fffu + ((u >> 16) & 1u)) >> 16;
    return (u16)u;
}

__device__ __forceinline__ f32x4 mfma16(bf16x8 a, bf16x8 b, f32x4 c) {
    return __builtin_amdgcn_mfma_f32_16x16x32_bf16(a, b, c, 0, 0, 0);
}
__device__ __forceinline__ f32x16 mfma32(bf16x8 a, bf16x8 b, f32x16 c) {
    return __builtin_amdgcn_mfma_f32_32x32x16_bf16(a, b, c, 0, 0, 0);
}

__device__ __forceinline__ void gload16(const void* g, void* lds) {
    auto gp = (__attribute__((address_space(1))) void*)(uintptr_t)g;
    auto lp = (__attribute__((address_space(3))) void*)(uintptr_t)lds;
    __builtin_amdgcn_global_load_lds(gp, lp, 16, 0, 0);
}

// bijective XCD-aware swizzle (m204); bm fastest so co-resident blocks share B panels
__device__ __forceinline__ int2 swz_bmbn(int nbm) {
    const int nwg = gridDim.x, orig = blockIdx.x;
    const int q = nwg >> 3, r = nwg & 7;
    const int xcd = orig & 7, lin = orig >> 3;
    const int id = (xcd < r ? xcd * (q + 1) : r * (q + 1) + (xcd - r) * q) + lin;
    return make_int2(id % nbm, id / nbm);
}

// ---------------------------------------------------------------------------
// HEAD: 256x256, 8 waves, ring-4 half-slots (K=32). R6 body (best measured).
// ---------------------------------------------------------------------------
__global__ __launch_bounds__(512, 2) void gemm_head_k(
    const u16* __restrict__ A, const u16* __restrict__ Bt,
    float* __restrict__ out, int M, int N)
{
    constexpr int KV = 1024;
    constexpr int H  = KV >> 5;                      // 32 half-slots
    __shared__ __align__(16) u16 lsA[4][256 * 32];
    __shared__ __align__(16) u16 lsB[4][256 * 32];
    const int nbm = M >> 8;
    const int2 bb = swz_bmbn(nbm);
    const int m0 = bb.x * 256, n0 = bb.y * 256;
    const int tid = threadIdx.x;
    const int w = tid >> 6, lane = tid & 63;
    const int wr = (w >> 2) * 128, wc = (w & 3) * 64;
    const int lr = lane & 15, lg = lane >> 4;
    const int rsw = (lg ^ ((lr >> 1) & 3)) * 8;

    const int trow = tid >> 2;
    const int ksw8 = ((tid & 3) ^ ((tid >> 3) & 3)) * 8;
    const u16* aA = A  + (size_t)(m0 + trow) * KV + ksw8;
    const u16* aB = Bt + (size_t)(n0 + trow) * KV + ksw8;
    u16* dA = &lsA[0][0] + trow * 32 + (tid & 3) * 8;
    u16* dB = &lsB[0][0] + trow * 32 + (tid & 3) * 8;

    f32x4 acc[8][4] = {};

    auto stage = [&](int h) {
        const int sl = h & 3;
        const int ko = h * 32;
        gload16(aA + ko,                      dA + sl * 8192);
        gload16(aA + ko + (size_t)128 * KV,   dA + sl * 8192 + 4096);
        gload16(aB + ko,                      dB + sl * 8192);
        gload16(aB + ko + (size_t)128 * KV,   dB + sl * 8192 + 4096);
    };

    bf16x8 ra0[8], rb0[4], ra1[8], rb1[4];            // two named sets (rule #20)
    auto lread = [&](bf16x8* af, bf16x8* bf, int h) {
        const int sl = h & 3;
#pragma unroll
        for (int m = 0; m < 8; m++)
            af[m] = *(const bf16x8*)&lsA[sl][(wr + m * 16 + lr) * 32 + rsw];
#pragma unroll
        for (int n = 0; n < 4; n++)
            bf[n] = *(const bf16x8*)&lsB[sl][(wc + n * 16 + lr) * 32 + rsw];
    };
    auto mm = [&](bf16x8* af, bf16x8* bf) {
        __builtin_amdgcn_s_setprio(1);
#pragma unroll
        for (int m = 0; m < 8; m++)
#pragma unroll
            for (int n = 0; n < 4; n++)
                acc[m][n] = mfma16(af[m], bf[n], acc[m][n]);
        __builtin_amdgcn_s_setprio(0);
    };

    auto body = [&](int h, bf16x8* aC, bf16x8* bC, bf16x8* aN, bf16x8* bN) {
        if (h + 3 < H) stage(h + 3);
        asm volatile("s_waitcnt lgkmcnt(0)" ::: "memory");
        const int rem = H - 1 - h;
        if (rem >= 3)      asm volatile("s_waitcnt vmcnt(8)" ::: "memory");
        else if (rem == 2) asm volatile("s_waitcnt vmcnt(4)" ::: "memory");
        else if (rem == 1) asm volatile("s_waitcnt vmcnt(0)" ::: "memory");
        __builtin_amdgcn_s_barrier();
        __builtin_amdgcn_sched_barrier(0);
        if (h + 1 < H) lread(aN, bN, h + 1);
        mm(aC, bC);
    };

    stage(0); stage(1); stage(2);
    asm volatile("s_waitcnt vmcnt(8)" ::: "memory");  // slot 0 landed
    __builtin_amdgcn_s_barrier();
    lread(ra0, rb0, 0);

#pragma unroll
    for (int h = 0; h < H; h += 2) {
        body(h,     ra0, rb0, ra1, rb1);
        body(h + 1, ra1, rb1, ra0, rb0);
    }

#pragma unroll
    for (int m = 0; m < 8; m++) {
        const int gr = m0 + wr + m * 16 + lg * 4;
#pragma unroll
        for (int r = 0; r < 4; r++) {
            float* orow = out + (size_t)(gr + r) * N + n0 + wc + lr;
#pragma unroll
            for (int n = 0; n < 4; n++)
                orow[n * 16] = acc[m][n][r];
        }
    }
}

// ---------------------------------------------------------------------------
// Deep-pipelined 128^2 GEMM (ring-4, counted vmcnt, one barrier per half-slot,
// one-slot-ahead regs, R6-style free-scheduled read+MFMA region). 2 blocks/CU.
// EPI: 0 bias->bf16, 1 bias+gelu->bf16, 4 f32 split-K partial,
//      5 bias->bf16 BUT blocks with n0>=2048 (V columns of qkv) write ONLY a
//        transposed copy into out2 [d][t] via LDS (qkvb V region never read).
// ---------------------------------------------------------------------------
template <int KC, int EPI>
__global__ __launch_bounds__(256, 2) void gemm_deep_k(
    const u16* __restrict__ A, int lda, const u16* __restrict__ Bt, int ldb,
    const float* __restrict__ bias, float* __restrict__ outf,
    u16* __restrict__ outb, int N, int nbm, int sk, long long sOut,
    u16* __restrict__ out2)
{
    constexpr int MF   = 4;
    constexpr int NF   = 4;
    constexpr int SLOT = 128 * 32;
    constexpr int HALF = 64 * 32;
    constexpr int H    = KC >> 5;

    __shared__ __align__(16) u16 lds[8 * SLOT];      // 64 KB: lsA | lsB
    u16 (*lsA)[SLOT] = (u16(*)[SLOT])lds;
    u16 (*lsB)[SLOT] = (u16(*)[SLOT])(lds + 4 * SLOT);

    const int s = blockIdx.y;
    A  += (size_t)s * sk;
    Bt += (size_t)s * sk;
    if (EPI == 4) outf += (size_t)s * sOut;

    const int2 bb = swz_bmbn(nbm);
    const int m0 = bb.x * 128, n0 = bb.y * 128;
    const int tid = threadIdx.x;
    const int w = tid >> 6, lane = tid & 63;
    const int wr = (w >> 1) * 64, wc = (w & 1) * 64;
    const int lr = lane & 15, lg = lane >> 4;
    const int rsw = (lg ^ ((lr >> 1) & 3)) * 8;

    const int trow = tid >> 2;
    const int ksw8 = ((tid & 3) ^ ((tid >> 3) & 3)) * 8;
    const u16* aA = A  + (size_t)(m0 + trow) * lda + ksw8;
    const u16* aB = Bt + (size_t)(n0 + trow) * ldb + ksw8;
    u16* dA = lds + trow * 32 + (tid & 3) * 8;
    u16* dB = lds + 4 * SLOT + trow * 32 + (tid & 3) * 8;

    f32x4 acc[MF][NF] = {};

    auto stage = [&](int h) {
        const int sl = h & 3;
        const int koff = h * 32;
        gload16(aA + koff,                     dA + sl * SLOT);
        gload16(aA + koff + (size_t)64 * lda,  dA + sl * SLOT + HALF);
        gload16(aB + koff,                     dB + sl * SLOT);
        gload16(aB + koff + (size_t)64 * ldb,  dB + sl * SLOT + HALF);
    };

    bf16x8 ra0[MF], rb0[NF], ra1[MF], rb1[NF];
    auto lread = [&](bf16x8* af, bf16x8* bf, int h) {
        const int sl = h & 3;
#pragma unroll
        for (int m = 0; m < MF; m++)
            af[m] = *(const bf16x8*)&lsA[sl][(wr + m * 16 + lr) * 32 + rsw];
#pragma unroll
        for (int n = 0; n < NF; n++)
            bf[n] = *(const bf16x8*)&lsB[sl][(wc + n * 16 + lr) * 32 + rsw];
    };

    auto body = [&](int h, bf16x8* aC, bf16x8* bC, bf16x8* aN, bf16x8* bN) {
        if (h + 3 < H) stage(h + 3);
        asm volatile("s_waitcnt lgkmcnt(0)" ::: "memory");
        const int rem = H - 1 - h;
        if (rem >= 3)      asm volatile("s_waitcnt vmcnt(8)" ::: "memory");
        else if (rem == 2) asm volatile("s_waitcnt vmcnt(4)" ::: "memory");
        else if (rem == 1) asm volatile("s_waitcnt vmcnt(0)" ::: "memory");
        __builtin_amdgcn_s_barrier();
        __builtin_amdgcn_sched_barrier(0);
        if (h + 1 < H) lread(aN, bN, h + 1);
        __builtin_amdgcn_s_setprio(1);
#pragma unroll
        for (int m = 0; m < MF; m++)
#pragma unroll
            for (int n = 0; n < NF; n++)
                acc[m][n] = mfma16(aC[m], bC[n], acc[m][n]);
        __builtin_amdgcn_s_setprio(0);
    };

    stage(0); stage(1); stage(2);
    asm volatile("s_waitcnt vmcnt(8)" ::: "memory");
    __builtin_amdgcn_s_barrier();
    lread(ra0, rb0, 0);

#pragma unroll
    for (int h = 0; h < H; h += 2) {
        body(h,     ra0, rb0, ra1, rb1);
        body(h + 1, ra1, rb1, ra0, rb0);
    }

    if constexpr (EPI == 5) {
        if (n0 >= 2048) {
            // V-columns block: write ONLY the transposed tile into out2 [d][t].
            __syncthreads();                          // staging LDS now reusable
            u16* tb = lds;                            // [128 d][132 t] = 33 KB
#pragma unroll
            for (int n = 0; n < NF; n++) {
                const int dl = wc + n * 16 + lr;      // local d
                const float bv = bias[n0 + dl];
#pragma unroll
                for (int m = 0; m < MF; m++) {
                    const int tl = wr + m * 16 + lg * 4;  // local t
#pragma unroll
                    for (int r = 0; r < 4; r++)
                        tb[dl * 132 + tl + r] = f2b(acc[m][n][r] + bv);
                }
            }
            __syncthreads();
#pragma unroll
            for (int it = 0; it < 16; ++it) {
                const int row = it * 8 + (tid >> 5);
                const uint2 v = *(const uint2*)&tb[row * 132 + (tid & 31) * 4];
                *(uint2*)&out2[(size_t)(n0 - 2048 + row) * 2048 + m0 + (tid & 31) * 4] = v;
            }
            return;
        }
    }

#pragma unroll
    for (int n = 0; n < NF; n++) {
        const int gc = n0 + wc + n * 16 + lr;
        float bv = 0.f;
        if constexpr (EPI == 0 || EPI == 1 || EPI == 5) bv = bias[gc];
#pragma unroll
        for (int m = 0; m < MF; m++) {
            const int grb = m0 + wr + m * 16 + lg * 4;
#pragma unroll
            for (int r = 0; r < 4; r++) {
                float v = acc[m][n][r] + bv;
                if constexpr (EPI == 1) v = 0.5f * v * (1.f + erff(v * 0.70710678118654752f));
                const size_t o = (size_t)(grb + r) * N + gc;
                if constexpr (EPI == 4) outf[o] = v;
                else                    outb[o] = f2b(v);
            }
        }
    }
}

// ---------------------------------------------------------------------------
// Split-K reduce + residual + bias, fused with the FOLLOWING LayerNorm.
// ---------------------------------------------------------------------------
__global__ __launch_bounds__(256) void reduce_ln_k(
    const float* __restrict__ pbuf, int S,
    const float* __restrict__ bias,
    float* __restrict__ x,
    const float* __restrict__ g, const float* __restrict__ bln,
    u16* __restrict__ hb)
{
    __shared__ float red[8];
    const int row = blockIdx.x, tid = threadIdx.x;
    const int w = tid >> 6, lane = tid & 63;
    const size_t base = (size_t)row * 256 + tid;
    float4 v = ((const float4*)x)[base];
    for (int s = 0; s < S; ++s) {
        const float4 p = ((const float4*)pbuf)[(size_t)s * 524288 + base];
        v.x += p.x; v.y += p.y; v.z += p.z; v.w += p.w;
    }
    const float4 bb = ((const float4*)bias)[tid];
    v.x += bb.x; v.y += bb.y; v.z += bb.z; v.w += bb.w;
    ((float4*)x)[base] = v;

    float s1 = v.x + v.y + v.z + v.w;
#pragma unroll
    for (int d = 1; d < 64; d <<= 1) s1 += __shfl_xor(s1, d);
    if (lane == 0) red[w] = s1;
    __syncthreads();
    const float mu = (red[0] + red[1] + red[2] + red[3]) * (1.f / 1024.f);
    const float d0 = v.x - mu, d1 = v.y - mu, d2 = v.z - mu, d3 = v.w - mu;
    float s2 = d0 * d0 + d1 * d1 + d2 * d2 + d3 * d3;
#pragma unroll
    for (int d = 1; d < 64; d <<= 1) s2 += __shfl_xor(s2, d);
    if (lane == 0) red[4 + w] = s2;
    __syncthreads();
    const float var = (red[4] + red[5] + red[6] + red[7]) * (1.f / 1024.f);
    const float rs = rsqrtf(var + 1e-5f);
    const float4 gv = ((const float4*)g)[tid];
    const float4 bv = ((const float4*)bln)[tid];
    u32 p0 = (u32)f2b(d0 * rs * gv.x + bv.x) | ((u32)f2b(d1 * rs * gv.y + bv.y) << 16);
    u32 p1 = (u32)f2b(d2 * rs * gv.z + bv.z) | ((u32)f2b(d3 * rs * gv.w + bv.w) << 16);
    ((uint2*)(hb + (size_t)row * 1024))[tid] = make_uint2(p0, p1);
}

// ---------------------------------------------------------------------------
// Flash attention, swapped-operand 32x32x16 structure (m214 port).
// ---------------------------------------------------------------------------
__global__ __launch_bounds__(256) void flash_attn_k(
    const u16* __restrict__ qkv, const u16* __restrict__ vT, u16* __restrict__ out)
{
    constexpr int DS = 3072, T = 2048;
    __shared__ float mrg[2][64][32];
    __shared__ float msh[2][32], lsh[2][32];
    __shared__ u16   sbuf[2][32 * 68];
    const int w = threadIdx.x >> 6, lane = threadIdx.x & 63;
    const int lq = lane & 31, hi = lane >> 5;
    const int hoff = blockIdx.y * 64;
    const int pair = w >> 1, par = w & 1;
    const int qt = (pair == 0) ? blockIdx.x : 63 - blockIdx.x;
    const int q0 = qt * 32;
    const int qg = q0 + lq;

    const u16* qp = qkv + (size_t)qg * DS + hoff;
    const u16* kp = qkv + 1024 + hoff;

    bf16x8 qf[4];
#pragma unroll
    for (int d = 0; d < 4; d++)
        qf[d] = *(const bf16x8*)(qp + d * 16 + hi * 8);

    f32x16 o0 = {}, o1 = {};
    float m_r = -1e30f, l_r = 0.f;

    const int ntiles = (qt >> 1) + 1;
    for (int t = par; t < ntiles; t += 2) {
        const int kv0 = t * 64;
        f32x16 s0 = {}, s1 = {};
        {
            const u16* kb0 = kp + (size_t)(kv0 + lq) * DS + hi * 8;
            const u16* kb1 = kb0 + (size_t)32 * DS;
#pragma unroll
            for (int d = 0; d < 4; d++) {
                s0 = mfma32(*(const bf16x8*)(kb0 + d * 16), qf[d], s0);
                s1 = mfma32(*(const bf16x8*)(kb1 + d * 16), qf[d], s1);
            }
        }
        float p[32];
        float mx = -1e30f;
#pragma unroll
        for (int r = 0; r < 16; r++) {
            const int kvl = (r & 3) + 8 * (r >> 2) + 4 * hi;
            float v0 = (kv0 + kvl      <= qg) ? s0[r] * 0.125f : -1e30f;
            float v1 = (kv0 + 32 + kvl <= qg) ? s1[r] * 0.125f : -1e30f;
            p[r] = v0; p[16 + r] = v1;
            mx = fmaxf(mx, fmaxf(v0, v1));
        }
        mx = fmaxf(mx, __shfl_xor(mx, 32));
        const float mn = fmaxf(m_r, mx);
        const float alpha = __expf(m_r - mn);
        m_r = mn;
        float ls = 0.f;
#pragma unroll
        for (int i = 0; i < 32; i++) { p[i] = __expf(p[i] - mn); ls += p[i]; }
        ls += __shfl_xor(ls, 32);
        l_r = l_r * alpha + ls;
#pragma unroll
        for (int r = 0; r < 16; r++) { o0[r] *= alpha; o1[r] *= alpha; }
#pragma unroll
        for (int sub = 0; sub < 2; sub++) {
            u32 pw[8], x[8];
#pragma unroll
            for (int i = 0; i < 8; i++)
                pw[i] = (u32)f2b(p[sub * 16 + 2 * i]) | ((u32)f2b(p[sub * 16 + 2 * i + 1]) << 16);
#pragma unroll
            for (int i = 0; i < 8; i++) x[i] = __shfl_xor(pw[i], 32);
            u32 b0[4], b1[4];
            b0[0] = hi ? x[2]  : pw[0];  b0[1] = hi ? x[3]  : pw[1];
            b0[2] = hi ? pw[2] : x[0];   b0[3] = hi ? pw[3] : x[1];
            b1[0] = hi ? x[6]  : pw[4];  b1[1] = hi ? x[7]  : pw[5];
            b1[2] = hi ? pw[6] : x[4];   b1[3] = hi ? pw[7] : x[5];
            bf16x8 B0 = __builtin_bit_cast(bf16x8, *(const uint4*)b0);
            bf16x8 B1 = __builtin_bit_cast(bf16x8, *(const uint4*)b1);
            const u16* vb = vT + (size_t)(hoff + lq) * T + kv0 + sub * 32 + hi * 8;
            o0 = mfma32(*(const bf16x8*)vb, B0, o0);
            o0 = mfma32(*(const bf16x8*)(vb + 16), B1, o0);
            const u16* vb1 = vb + (size_t)32 * T;
            o1 = mfma32(*(const bf16x8*)vb1, B0, o1);
            o1 = mfma32(*(const bf16x8*)(vb1 + 16), B1, o1);
        }
    }

    __syncthreads();
    if (par == 0) {
#pragma unroll
        for (int r = 0; r < 16; r++) {
            const int d = (r & 3) + 8 * (r >> 2) + 4 * hi;
            mrg[pair][d][lq]      = o0[r];
            mrg[pair][d + 32][lq] = o1[r];
        }
        if (hi == 0) { msh[pair][lq] = m_r; lsh[pair][lq] = l_r; }
    }
    __syncthreads();
    if (par == 1) {
        const float m0v = msh[pair][lq], l0v = lsh[pair][lq];
        const float M = fmaxf(m0v, m_r);
        const float f0 = __expf(m0v - M), f1 = __expf(m_r - M);
        const float linv = 1.f / (l0v * f0 + l_r * f1);
        u32* sb = (u32*)sbuf[pair];
#pragma unroll
        for (int r = 0; r < 16; r += 2) {
            const int d = (r & 3) + 8 * (r >> 2) + 4 * hi;
            float va = (mrg[pair][d][lq] * f0 + o0[r] * f1) * linv;
            float vb = (mrg[pair][d + 1][lq] * f0 + o0[r + 1] * f1) * linv;
            sb[lq * 34 + (d >> 1)] = (u32)f2b(va) | ((u32)f2b(vb) << 16);
            float vc = (mrg[pair][d + 32][lq] * f0 + o1[r] * f1) * linv;
            float vd = (mrg[pair][d + 33][lq] * f0 + o1[r + 1] * f1) * linv;
            sb[lq * 34 + ((d + 32) >> 1)] = (u32)f2b(vc) | ((u32)f2b(vd) << 16);
        }
#pragma unroll
        for (int ps = 0; ps < 8; ps++) {
            const int row = ps * 4 + (lane >> 4);
            const uint2 v = *(const uint2*)&sbuf[pair][row * 68 + (lane & 15) * 4];
            *(uint2*)(out + (size_t)(q0 + row) * 1024 + hoff + (lane & 15) * 4) = v;
        }
    }
}

// ---------------------------------------------------------------------------
// Transpose+convert, 64x64 tile: FULL 128B-line writes. src [K][N] f32 ->
// dst [N][K] bf16, per-z strides.
// ---------------------------------------------------------------------------
__global__ __launch_bounds__(256) void transpose_cvt64_k(
    const float* __restrict__ src, u16* __restrict__ dst, int K, int N,
    long long srcLS, long long dstLS)
{
    __shared__ float tf[64][68];
    src += (size_t)blockIdx.z * srcLS;
    dst += (size_t)blockIdx.z * dstLS;
    const int n0 = blockIdx.x * 64, k0 = blockIdx.y * 64;
    const int tid = threadIdx.x;
    const int c4 = tid & 15, rr = tid >> 4;
#pragma unroll
    for (int p = 0; p < 4; ++p) {
        const int k = rr + p * 16;
        *(float4*)&tf[k][c4 * 4] = *(const float4*)&src[(size_t)(k0 + k) * N + n0 + c4 * 4];
    }
    __syncthreads();
    const int kq = (tid & 15) * 4, nn = tid >> 4;
#pragma unroll
    for (int p = 0; p < 4; ++p) {
        const int n = nn + p * 16;
        const u32 lo = (u32)f2b(tf[kq + 0][n]) | ((u32)f2b(tf[kq + 1][n]) << 16);
        const u32 hi = (u32)f2b(tf[kq + 2][n]) | ((u32)f2b(tf[kq + 3][n]) << 16);
        *(uint2*)&dst[(size_t)(n0 + n) * K + k0 + kq] = make_uint2(lo, hi);
    }
}

// Same, for the 12 q/k/v weight matrices in one launch. z = layer*3 + matrix.
__global__ __launch_bounds__(256) void transpose_cvt64_qkv_k(
    const float* __restrict__ Wq, const float* __restrict__ Wk,
    const float* __restrict__ Wv, u16* __restrict__ qkvT)
{
    __shared__ float tf[64][68];
    const int z = blockIdx.z, l = z / 3, m = z % 3;
    const float* src = (m == 0 ? Wq : (m == 1 ? Wk : Wv)) + (size_t)l * 1048576;
    u16* dst = qkvT + (size_t)l * 3145728 + (size_t)m * 1048576;
    const int n0 = blockIdx.x * 64, k0 = blockIdx.y * 64;
    const int tid = threadIdx.x;
    const int c4 = tid & 15, rr = tid >> 4;
#pragma unroll
    for (int p = 0; p < 4; ++p) {
        const int k = rr + p * 16;
        *(float4*)&tf[k][c4 * 4] = *(const float4*)&src[(size_t)(k0 + k) * 1024 + n0 + c4 * 4];
    }
    __syncthreads();
    const int kq = (tid & 15) * 4, nn = tid >> 4;
#pragma unroll
    for (int p = 0; p < 4; ++p) {
        const int n = nn + p * 16;
        const u32 lo = (u32)f2b(tf[kq + 0][n]) | ((u32)f2b(tf[kq + 1][n]) << 16);
        const u32 hi = (u32)f2b(tf[kq + 2][n]) | ((u32)f2b(tf[kq + 3][n]) << 16);
        *(uint2*)&dst[(size_t)(n0 + n) * 1024 + k0 + kq] = make_uint2(lo, hi);
    }
}

__global__ __launch_bounds__(256) void concat_bias_k(
    const float* __restrict__ bq, const float* __restrict__ bk,
    const float* __restrict__ bv, float* __restrict__ bcat)
{
    const int l = blockIdx.y;
    const int j = blockIdx.x * 256 + threadIdx.x;
    float v;
    if (j < 1024)      v = bq[l * 1024 + j];
    else if (j < 2048) v = bk[l * 1024 + j - 1024];
    else               v = bv[l * 1024 + j - 2048];
    bcat[l * 3072 + j] = v;
}

// ---------------------------------------------------------------------------
// Fused embedding + positional encoding + LayerNorm (ln1 of layer 0).
// ---------------------------------------------------------------------------
__global__ __launch_bounds__(256) void embed_ln_k(
    const int* __restrict__ idx, const float* __restrict__ emb,
    const float* __restrict__ g, const float* __restrict__ b,
    float* __restrict__ x, u16* __restrict__ out)
{
    __shared__ float red[8];
    const int t = blockIdx.x, tid = threadIdx.x;
    const int w = tid >> 6, lane = tid & 63;
    const int tok = idx[t];
    float4 v = ((const float4*)(emb + (size_t)tok * 1024))[tid];
    const int d0i = tid * 4;
    const float c = -0.0089944730195080f;      // -ln(10000)/1024
    const float a0 = (float)t * expf((float)d0i * c);
    const float a1 = (float)t * expf((float)(d0i + 2) * c);
    v.x += sinf(a0); v.y += cosf(a0); v.z += sinf(a1); v.w += cosf(a1);
    ((float4*)(x + (size_t)t * 1024))[tid] = v;

    float s1 = v.x + v.y + v.z + v.w;
#pragma unroll
    for (int d = 1; d < 64; d <<= 1) s1 += __shfl_xor(s1, d);
    if (lane == 0) red[w] = s1;
    __syncthreads();
    const float mu = (red[0] + red[1] + red[2] + red[3]) * (1.f / 1024.f);
    const float d0 = v.x - mu, d1 = v.y - mu, d2 = v.z - mu, d3 = v.w - mu;
    float s2 = d0 * d0 + d1 * d1 + d2 * d2 + d3 * d3;
#pragma unroll
    for (int d = 1; d < 64; d <<= 1) s2 += __shfl_xor(s2, d);
    if (lane == 0) red[4 + w] = s2;
    __syncthreads();
    const float var = (red[4] + red[5] + red[6] + red[7]) * (1.f / 1024.f);
    const float rs = rsqrtf(var + 1e-5f);
    const float4 gv = ((const float4*)g)[tid];
    const float4 bv = ((const float4*)b)[tid];
    u32 p0 = (u32)f2b(d0 * rs * gv.x + bv.x) | ((u32)f2b(d1 * rs * gv.y + bv.y) << 16);
    u32 p1 = (u32)f2b(d2 * rs * gv.z + bv.z) | ((u32)f2b(d3 * rs * gv.w + bv.w) << 16);
    ((uint2*)(out + (size_t)t * 1024))[tid] = make_uint2(p0, p1);
}

// ---------------------------------------------------------------------------
extern "C" void kernel_launch(void* const* d_in, const int* in_sizes, int n_in,
                              void* d_out, int out_size, void* d_ws, size_t ws_size,
                              hipStream_t stream)
{
    const int*   idx   = (const int*)  d_in[0];
    const float* embed = (const float*)d_in[1];
    const float* Wq    = (const float*)d_in[2];
    const float* Wk    = (const float*)d_in[3];
    const float* Wv    = (const float*)d_in[4];
    const float* Wo    = (const float*)d_in[5];
    const float* bq    = (const float*)d_in[6];
    const float* bk    = (const float*)d_in[7];
    const float* bv    = (const float*)d_in[8];
    const float* bo    = (const float*)d_in[9];
    const float* ln1g  = (const float*)d_in[10];
    const float* ln1b  = (const float*)d_in[11];
    const float* ln2g  = (const float*)d_in[12];
    const float* ln2b  = (const float*)d_in[13];
    const float* w1    = (const float*)d_in[14];
    const float* b1    = (const float*)d_in[15];
    const float* w2    = (const float*)d_in[16];
    const float* b2    = (const float*)d_in[17];
    const float* lnfg  = (const float*)d_in[18];
    const float* lnfb  = (const float*)d_in[19];
    const float* headw = (const float*)d_in[20];

    char* ws = (char*)d_ws;
    auto alloc = [&](size_t bytes) {
        char* p = ws;
        ws += (bytes + 255) & ~(size_t)255;
        return p;
    };
    u16*   qkvT = (u16*)alloc((size_t)4 * 3072 * 1024 * 2);
    u16*   WoT  = (u16*)alloc((size_t)4 * 1024 * 1024 * 2);
    u16*   w1T  = (u16*)alloc((size_t)4 * 1024 * 4096 * 2);
    u16*   w2T  = (u16*)alloc((size_t)4 * 1024 * 4096 * 2);
    u16*   hT   = (u16*)alloc((size_t)32000 * 1024 * 2);
    float* bcat = (float*)alloc((size_t)4 * 3072 * 4);
    float* x    = (float*)alloc((size_t)2048 * 1024 * 4);
    u16*   hb   = (u16*)alloc((size_t)2048 * 1024 * 2);
    u16*   qkvb = (u16*)alloc((size_t)2048 * 3072 * 2);
    u16*   vTb  = (u16*)alloc((size_t)2048 * 1024 * 2);
    u16*   ab   = (u16*)alloc((size_t)2048 * 1024 * 2);
    u16*   ff   = (u16*)alloc((size_t)2048 * 4096 * 2);
    float* pbuf = (float*)d_out;   // split-K partials; head GEMM overwrites at the end

    transpose_cvt64_qkv_k<<<dim3(16, 16, 12), 256, 0, stream>>>(Wq, Wk, Wv, qkvT);
    transpose_cvt64_k<<<dim3(16, 16, 4),  256, 0, stream>>>(Wo, WoT,    1024, 1024,  1048576, 1048576);
    transpose_cvt64_k<<<dim3(64, 16, 4),  256, 0, stream>>>(w1, w1T,    1024, 4096,  4194304, 4194304);
    transpose_cvt64_k<<<dim3(16, 64, 4),  256, 0, stream>>>(w2, w2T,    4096, 1024,  4194304, 4194304);
    transpose_cvt64_k<<<dim3(500, 16, 1), 256, 0, stream>>>(headw, hT,  1024, 32000, 0, 0);
    concat_bias_k<<<dim3(12, 4), 256, 0, stream>>>(bq, bk, bv, bcat);

    embed_ln_k<<<dim3(2048), 256, 0, stream>>>(idx, embed, ln1g, ln1b, x, hb);

    for (int l = 0; l < 4; ++l) {
        // qkv: 128^2 deep, N=3072; EPI5 -> V-column blocks write vTb transposed
        gemm_deep_k<1024, 5><<<dim3(384), 256, 0, stream>>>(
            hb, 1024, qkvT + (size_t)l * 3145728, 1024,
            bcat + l * 3072, nullptr, qkvb, 3072, 16, 0, 0, vTb);
        flash_attn_k<<<dim3(32, 16), 256, 0, stream>>>(qkvb, vTb, ab);
        // o-proj: split-K=2 (KC=512)
        gemm_deep_k<512, 4><<<dim3(128, 2), 256, 0, stream>>>(
            ab, 1024, WoT + (size_t)l * 1048576, 1024,
            nullptr, pbuf, nullptr, 1024, 16, 512, 2097152, nullptr);
        reduce_ln_k<<<dim3(2048), 256, 0, stream>>>(pbuf, 2, bo + l * 1024, x,
                                                    ln2g + l * 1024, ln2b + l * 1024, hb);
        // ffn1: gelu, N=4096
        gemm_deep_k<1024, 1><<<dim3(512), 256, 0, stream>>>(
            hb, 1024, w1T + (size_t)l * 4194304, 1024,
            b1 + l * 4096, nullptr, ff, 4096, 16, 0, 0, nullptr);
        // ffn2: split-K=4 (KC=1024 of 4096)
        gemm_deep_k<1024, 4><<<dim3(128, 4), 256, 0, stream>>>(
            ff, 4096, w2T + (size_t)l * 4194304, 4096,
            nullptr, pbuf, nullptr, 1024, 16, 1024, 2097152, nullptr);
        const float* ng = (l < 3) ? (ln1g + (l + 1) * 1024) : lnfg;
        const float* nb = (l < 3) ? (ln1b + (l + 1) * 1024) : lnfb;
        reduce_ln_k<<<dim3(2048), 256, 0, stream>>>(pbuf, 4, b2 + l * 1024, x, ng, nb, hb);
    }
    // head: 256^2, R6 body (best measured schedule)
    gemm_head_k<<<dim3(1000), 512, 0, stream>>>(hb, hT, (float*)d_out, 2048, 32000);
}